// Round 1
// baseline (254.511 us; speedup 1.0000x reference)
//
#include <hip/hip_runtime.h>
#include <stdint.h>

#define NB 32
#define NP 32768
#define NO 32
#define THRESH 0.35f

typedef unsigned long long u64;
typedef unsigned int u32;

__device__ __forceinline__ u64 shfl_xor_u64(u64 v, int m) {
    u32 lo = (u32)v, hi = (u32)(v >> 32);
    lo = (u32)__shfl_xor((int)lo, m, 64);
    hi = (u32)__shfl_xor((int)hi, m, 64);
    return ((u64)hi << 32) | (u64)lo;
}

// ---------------- Kernel A: IoU + per-prior best truth + per-truth best prior ----------
__global__ void kernA(const float* __restrict__ priors,
                      const float* __restrict__ targets,
                      float* __restrict__ bto,
                      unsigned char* __restrict__ bti,
                      u64* __restrict__ bpk)
{
#pragma clang fp contract(off)
    __shared__ float tb[NO][4];
    __shared__ float ta[NO];
    __shared__ u64 keys[NO];
    const int b = blockIdx.y;
    const int tid = threadIdx.x;
    if (tid < NO * 4) {
        int o = tid >> 2, c = tid & 3;
        tb[o][c] = targets[(b * NO + o) * 5 + c];
    }
    if (tid < NO) keys[tid] = 0ull;
    __syncthreads();
    if (tid < NO) ta[tid] = (tb[tid][2] - tb[tid][0]) * (tb[tid][3] - tb[tid][1]);
    __syncthreads();

    const int base = blockIdx.x * 1024;
    float px1[4], py1[4], px2[4], py2[4], ab[4];
    int pidx[4];
#pragma unroll
    for (int j = 0; j < 4; ++j) {
        int p = base + j * 256 + tid;
        pidx[j] = p;
        float4 pr = ((const float4*)priors)[p];
        px1[j] = pr.x - pr.z * 0.5f;
        py1[j] = pr.y - pr.w * 0.5f;
        px2[j] = pr.x + pr.z * 0.5f;
        py2[j] = pr.y + pr.w * 0.5f;
        ab[j]  = pr.z * pr.w;
    }
    float bestV[4] = {-1.f, -1.f, -1.f, -1.f};
    int bestO[4] = {0, 0, 0, 0};
    for (int o = 0; o < NO; ++o) {
        float tx1 = tb[o][0], ty1 = tb[o][1], tx2 = tb[o][2], ty2 = tb[o][3], aa = ta[o];
        u64 lk = 0;
#pragma unroll
        for (int j = 0; j < 4; ++j) {
            float iw = fminf(tx2, px2[j]) - fmaxf(tx1, px1[j]);
            float ih = fminf(ty2, py2[j]) - fmaxf(ty1, py1[j]);
            iw = fmaxf(iw, 0.f); ih = fmaxf(ih, 0.f);
            float inter = iw * ih;
            float iou = inter / (aa + ab[j] - inter);
            if (iou > bestV[j]) { bestV[j] = iou; bestO[j] = o; }  // strict > => first max, like argmax
            u64 key = ((u64)__float_as_uint(iou) << 32) | (u64)(~(u32)pidx[j]);  // ~p => smallest p on tie
            lk = (key > lk) ? key : lk;
        }
#pragma unroll
        for (int m = 32; m; m >>= 1) {
            u64 o2 = shfl_xor_u64(lk, m);
            lk = (o2 > lk) ? o2 : lk;
        }
        if ((tid & 63) == 0) atomicMax(&keys[o], lk);
    }
    __syncthreads();
    if (tid < NO) atomicMax(&bpk[b * NO + tid], keys[tid]);
#pragma unroll
    for (int j = 0; j < 4; ++j) {
        size_t gp = (size_t)b * NP + pidx[j];
        bto[gp] = bestV[j];
        bti[gp] = (unsigned char)bestO[j];
    }
}

// ---------------- Kernel B: apply the "force best prior" fix, in-order per batch -------
__global__ void kernB(const u64* __restrict__ bpk,
                      float* __restrict__ bto,
                      unsigned char* __restrict__ bti)
{
    int b = threadIdx.x;
    if (b >= NB) return;
    for (int o = 0; o < NO; ++o) {   // serial, in order: last write wins (matches scatter)
        u32 p = ~(u32)(bpk[b * NO + o] & 0xFFFFFFFFull);
        size_t gp = (size_t)b * NP + p;
        bto[gp] = 2.0f;
        bti[gp] = (unsigned char)o;
    }
}

// ---------------- Kernel C1: per-prior losses + mine array + per-batch stats -----------
__global__ void kernC1(const float* __restrict__ loc,
                       const float* __restrict__ conf,
                       const float* __restrict__ priors,
                       const float* __restrict__ targets,
                       const float* __restrict__ bto,
                       const unsigned char* __restrict__ bti,
                       float* __restrict__ mine,
                       float* __restrict__ batch_sl1,
                       float* __restrict__ batch_cep,
                       int* __restrict__ batch_npos)
{
#pragma clang fp contract(off)
    __shared__ float tb[NO][5];
    __shared__ float rs0[4], rs1[4];
    __shared__ int rc[4];
    const int b = blockIdx.y;
    const int tid = threadIdx.x;
    if (tid < NO * 5) tb[tid / 5][tid % 5] = targets[b * NO * 5 + tid];
    __syncthreads();
    const int base = blockIdx.x * 1024;
    float s_sl1 = 0.f, s_cep = 0.f;
    int np = 0;
#pragma unroll
    for (int j = 0; j < 4; ++j) {
        int p = base + j * 256 + tid;
        size_t gp = (size_t)b * NP + p;
        float ov = bto[gp];
        int o = (int)bti[gp];
        int cf = (ov < THRESH) ? 0 : ((int)tb[o][4] + 1);
        bool pos = cf > 0;
        float4 pr = ((const float4*)priors)[p];
        float mx1 = tb[o][0], my1 = tb[o][1], mx2 = tb[o][2], my2 = tb[o][3];
        float g0 = ((mx1 + mx2) * 0.5f - pr.x) / (0.1f * pr.z);
        float g1 = ((my1 + my2) * 0.5f - pr.y) / (0.1f * pr.w);
        float g2 = logf((mx2 - mx1) / pr.z) / 0.2f;
        float g3 = logf((my2 - my1) / pr.w) / 0.2f;
        float4 ld = ((const float4*)loc)[gp];
        float d0 = ld.x - g0, d1 = ld.y - g1, d2 = ld.z - g2, d3 = ld.w - g3;
        float a0 = fabsf(d0), a1 = fabsf(d1), a2 = fabsf(d2), a3 = fabsf(d3);
        float sl1 = (a0 < 1.f ? 0.5f * d0 * d0 : a0 - 0.5f)
                  + (a1 < 1.f ? 0.5f * d1 * d1 : a1 - 0.5f)
                  + (a2 < 1.f ? 0.5f * d2 * d2 : a2 - 0.5f)
                  + (a3 < 1.f ? 0.5f * d3 * d3 : a3 - 0.5f);
        float2 c = ((const float2*)conf)[gp];
        float mm = fmaxf(c.x, c.y);
        float lse = mm + logf(expf(c.x - mm) + expf(c.y - mm));
        float picked = (cf == 0) ? c.x : c.y;
        float ce = lse - picked;
        if (pos) { s_sl1 += sl1; s_cep += ce; np++; }
        mine[gp] = pos ? 0.f : ce;
    }
#pragma unroll
    for (int m = 32; m; m >>= 1) {
        s_sl1 += __shfl_xor(s_sl1, m, 64);
        s_cep += __shfl_xor(s_cep, m, 64);
        np    += __shfl_xor(np, m, 64);
    }
    int lane = tid & 63, w = tid >> 6;
    if (lane == 0) { rs0[w] = s_sl1; rs1[w] = s_cep; rc[w] = np; }
    __syncthreads();
    if (tid == 0) {
        float t0 = 0.f, t1 = 0.f; int t2 = 0;
        for (int i = 0; i < 4; ++i) { t0 += rs0[i]; t1 += rs1[i]; t2 += rc[i]; }
        atomicAdd(&batch_sl1[b], t0);
        atomicAdd(&batch_cep[b], t1);
        atomicAdd(&batch_npos[b], t2);
    }
}

// ---------------- Kernel C2: per-batch radix-select top-k sum of `mine` ----------------
__launch_bounds__(1024)
__global__ void kernC2(const float* __restrict__ mine,
                       const float* __restrict__ batch_cep,
                       const int* __restrict__ batch_npos,
                       float* __restrict__ loss_c_total)
{
    const int b = blockIdx.x;
    const int tid = threadIdx.x;
    __shared__ int hist[256];
    __shared__ u32 sh_prefix;
    __shared__ int sh_kk;
    __shared__ float rs[16];
    __shared__ int rc[16];
    const int npos = batch_npos[b];
    const int k = min(7 * npos, NP - 1);
    const float cep = batch_cep[b];
    const float* mb = mine + (size_t)b * NP;
    float topk = 0.f;
    if (k > 0) {
        if (tid == 0) { sh_prefix = 0u; sh_kk = k; }
        __syncthreads();
        for (int pass = 0; pass < 4; ++pass) {
            if (tid < 256) hist[tid] = 0;
            __syncthreads();
            const int shift = 24 - 8 * pass;
            const u32 prefix = sh_prefix;
            for (int i = tid; i < NP; i += 1024) {
                u32 key = __float_as_uint(mb[i]);
                u32 hi = (u32)(((u64)key) >> (shift + 8));  // 64-bit shift: defined at 32
                if (hi == prefix) atomicAdd(&hist[(key >> shift) & 0xFF], 1);
            }
            __syncthreads();
            if (tid == 0) {
                int kk = sh_kk, cum = 0, sel = 0;
                for (int bin = 255; bin >= 0; --bin) {
                    int c = hist[bin];
                    if (cum + c >= kk) { sel = bin; sh_kk = kk - cum; break; }
                    cum += c;
                }
                sh_prefix = (prefix << 8) | (u32)sel;
            }
            __syncthreads();
        }
        const u32 T = sh_prefix;
        const float tval = __uint_as_float(T);
        float s = 0.f; int c = 0;
        for (int i = tid; i < NP; i += 1024) {
            float v = mb[i];
            u32 key = __float_as_uint(v);
            if (key > T) { s += v; c++; }
        }
#pragma unroll
        for (int m = 32; m; m >>= 1) {
            s += __shfl_xor(s, m, 64);
            c += __shfl_xor(c, m, 64);
        }
        int lane = tid & 63, w = tid >> 6;
        if (lane == 0) { rs[w] = s; rc[w] = c; }
        __syncthreads();
        if (tid == 0) {
            float st = 0.f; int ct = 0;
            for (int i = 0; i < 16; ++i) { st += rs[i]; ct += rc[i]; }
            topk = st + (float)(k - ct) * tval;  // ties at threshold: all equal value
        }
    }
    if (tid == 0) atomicAdd(loss_c_total, cep + topk);
}

// ---------------- Kernel D: finalize ----------------------------------------------------
__global__ void kernD(const float* __restrict__ batch_sl1,
                      const int* __restrict__ batch_npos,
                      const float* __restrict__ loss_c_total,
                      float* __restrict__ out)
{
    int tid = threadIdx.x;
    float s = (tid < NB) ? batch_sl1[tid] : 0.f;
    int   n = (tid < NB) ? batch_npos[tid] : 0;
#pragma unroll
    for (int m = 32; m; m >>= 1) {
        s += __shfl_xor(s, m, 64);
        n += __shfl_xor(n, m, 64);
    }
    if (tid == 0) {
        float N = fmaxf((float)n, 1.f);
        out[0] = s / N;
        out[1] = loss_c_total[0] / N;
    }
}

extern "C" void kernel_launch(void* const* d_in, const int* in_sizes, int n_in,
                              void* d_out, int out_size, void* d_ws, size_t ws_size,
                              hipStream_t stream) {
    const float* loc     = (const float*)d_in[0];   // (B,P,4)
    const float* conf    = (const float*)d_in[1];   // (B,P,2)
    const float* priors  = (const float*)d_in[2];   // (P,4)
    const float* targets = (const float*)d_in[3];   // (B,O,5)
    float* out = (float*)d_out;

    char* ws = (char*)d_ws;
    // header: bpk[NB*NO] u64 (8192 B), batch_sl1[32], batch_cep[32], batch_npos[32], loss_c_total
    u64*   bpk          = (u64*)ws;                          // 0     .. 8192
    float* batch_sl1    = (float*)(ws + 8192);               // 8192  .. 8320
    float* batch_cep    = (float*)(ws + 8320);               // 8320  .. 8448
    int*   batch_npos   = (int*)(ws + 8448);                 // 8448  .. 8576
    float* loss_c_total = (float*)(ws + 8576);               // 8576  .. 8580
    const size_t H = 8704;
    float*         bto  = (float*)(ws + H);                            // 4 MB
    unsigned char* bti  = (unsigned char*)(ws + H + 4ull * NB * NP);   // 1 MB
    float*         mine = (float*)(ws + H + 5ull * NB * NP);           // 4 MB

    hipMemsetAsync(ws, 0, H, stream);

    dim3 gA(NP / 1024, NB);
    kernA<<<gA, 256, 0, stream>>>(priors, targets, bto, bti, bpk);
    kernB<<<1, 64, 0, stream>>>(bpk, bto, bti);
    dim3 gC(NP / 1024, NB);
    kernC1<<<gC, 256, 0, stream>>>(loc, conf, priors, targets, bto, bti, mine,
                                   batch_sl1, batch_cep, batch_npos);
    kernC2<<<NB, 1024, 0, stream>>>(mine, batch_cep, batch_npos, loss_c_total);
    kernD<<<1, 64, 0, stream>>>(batch_sl1, batch_npos, loss_c_total, out);
}

// Round 2
// 164.519 us; speedup vs baseline: 1.5470x; 1.5470x over previous
//
#include <hip/hip_runtime.h>
#include <stdint.h>

#define NB 32
#define NP 32768
#define NO 32
#define THRESH 0.35f

typedef unsigned long long u64;
typedef unsigned int u32;

// ---------------- Kernel A: IoU + per-prior best truth + per-truth best prior ----------
__global__ void kernA(const float* __restrict__ priors,
                      const float* __restrict__ targets,
                      float* __restrict__ bto,
                      unsigned char* __restrict__ bti,
                      u64* __restrict__ bpk)
{
#pragma clang fp contract(off)
    __shared__ __align__(16) float tb[NO][4];
    __shared__ float ta[NO];
    __shared__ u64 keys[NO];
    const int b = blockIdx.y;
    const int tid = threadIdx.x;
    if (tid < NO * 4) {
        int o = tid >> 2, c = tid & 3;
        tb[o][c] = targets[(b * NO + o) * 5 + c];
    }
    if (tid < NO) keys[tid] = 0ull;
    __syncthreads();
    if (tid < NO) ta[tid] = (tb[tid][2] - tb[tid][0]) * (tb[tid][3] - tb[tid][1]);
    __syncthreads();

    const int base = blockIdx.x * 1024;
    float px1[4], py1[4], px2[4], py2[4], ab[4];
    int pidx[4];
#pragma unroll
    for (int j = 0; j < 4; ++j) {
        int p = base + j * 256 + tid;
        pidx[j] = p;
        float4 pr = ((const float4*)priors)[p];
        px1[j] = pr.x - pr.z * 0.5f;
        py1[j] = pr.y - pr.w * 0.5f;
        px2[j] = pr.x + pr.z * 0.5f;
        py2[j] = pr.y + pr.w * 0.5f;
        ab[j]  = pr.z * pr.w;
    }
    float bestV[4] = {-1.f, -1.f, -1.f, -1.f};
    int bestO[4] = {0, 0, 0, 0};
    const int lane_o = tid & 31;   // stagger o per lane: spreads LDS atomics over 32 addrs
    for (int it = 0; it < NO; ++it) {
        const int o = (it + lane_o) & 31;
        float4 tt = ((const float4*)tb)[o];
        float tx1 = tt.x, ty1 = tt.y, tx2 = tt.z, ty2 = tt.w;
        float aa = ta[o];
        float iou[4];
#pragma unroll
        for (int j = 0; j < 4; ++j) {
            float iw = fminf(tx2, px2[j]) - fmaxf(tx1, px1[j]);
            float ih = fminf(ty2, py2[j]) - fmaxf(ty1, py1[j]);
            iw = fmaxf(iw, 0.f); ih = fmaxf(ih, 0.f);
            float inter = iw * ih;
            iou[j] = inter / (aa + ab[j] - inter);
            // per-prior best truth; explicit tie-break to smallest o (visit order is staggered)
            if (iou[j] > bestV[j] || (iou[j] == bestV[j] && o < bestO[j])) {
                bestV[j] = iou[j]; bestO[j] = o;
            }
        }
        // per-truth best prior: thread-local max (smallest p on ties), then filtered LDS atomic
        float bi = iou[3]; int bp = pidx[3];
#pragma unroll
        for (int j = 2; j >= 0; --j) {
            if (iou[j] >= bi) { bi = iou[j]; bp = pidx[j]; }
        }
        u64 key = ((u64)__float_as_uint(bi) << 32) | (u64)(~(u32)bp);
        u64 cur = keys[o];
        if (key > cur) atomicMax(&keys[o], key);   // prefilter: stale read only costs extra atomic
    }
    __syncthreads();
    if (tid < NO) atomicMax(&bpk[b * NO + tid], keys[tid]);
#pragma unroll
    for (int j = 0; j < 4; ++j) {
        size_t gp = (size_t)b * NP + pidx[j];
        bto[gp] = bestV[j];
        bti[gp] = (unsigned char)bestO[j];
    }
}

// ---------------- Kernel B: apply "force best prior" fix; last-writer-wins, parallel ----
__global__ void kernB(const u64* __restrict__ bpk,
                      float* __restrict__ bto,
                      unsigned char* __restrict__ bti)
{
    __shared__ u32 pp[NB][NO];
    const int t = threadIdx.x;            // 1024 threads: (b,o)
    const int b = t >> 5, o = t & 31;
    pp[b][o] = ~(u32)(bpk[b * NO + o] & 0xFFFFFFFFull);
    __syncthreads();
    u32 p = pp[b][o];
    bool last = true;
    for (int o2 = o + 1; o2 < NO; ++o2)
        if (pp[b][o2] == p) { last = false; break; }   // a later o writes same prior
    if (last) {
        size_t gp = (size_t)b * NP + p;
        bto[gp] = 2.0f;
        bti[gp] = (unsigned char)o;
    }
}

// ---------------- Kernel C1: per-prior losses + mine array + per-batch stats -----------
__global__ void kernC1(const float* __restrict__ loc,
                       const float* __restrict__ conf,
                       const float* __restrict__ priors,
                       const float* __restrict__ targets,
                       const float* __restrict__ bto,
                       const unsigned char* __restrict__ bti,
                       float* __restrict__ mine,
                       float* __restrict__ batch_sl1,
                       float* __restrict__ batch_cep,
                       int* __restrict__ batch_npos)
{
#pragma clang fp contract(off)
    __shared__ float tb[NO][5];
    __shared__ float rs0[4], rs1[4];
    __shared__ int rc[4];
    const int b = blockIdx.y;
    const int tid = threadIdx.x;
    if (tid < NO * 5) tb[tid / 5][tid % 5] = targets[b * NO * 5 + tid];
    __syncthreads();
    const int base = blockIdx.x * 1024;
    float s_sl1 = 0.f, s_cep = 0.f;
    int np = 0;
#pragma unroll
    for (int j = 0; j < 4; ++j) {
        int p = base + j * 256 + tid;
        size_t gp = (size_t)b * NP + p;
        float ov = bto[gp];
        int o = (int)bti[gp];
        int cf = (ov < THRESH) ? 0 : ((int)tb[o][4] + 1);
        bool pos = cf > 0;
        float4 pr = ((const float4*)priors)[p];
        float mx1 = tb[o][0], my1 = tb[o][1], mx2 = tb[o][2], my2 = tb[o][3];
        float g0 = ((mx1 + mx2) * 0.5f - pr.x) / (0.1f * pr.z);
        float g1 = ((my1 + my2) * 0.5f - pr.y) / (0.1f * pr.w);
        float g2 = logf((mx2 - mx1) / pr.z) / 0.2f;
        float g3 = logf((my2 - my1) / pr.w) / 0.2f;
        float4 ld = ((const float4*)loc)[gp];
        float d0 = ld.x - g0, d1 = ld.y - g1, d2 = ld.z - g2, d3 = ld.w - g3;
        float a0 = fabsf(d0), a1 = fabsf(d1), a2 = fabsf(d2), a3 = fabsf(d3);
        float sl1 = (a0 < 1.f ? 0.5f * d0 * d0 : a0 - 0.5f)
                  + (a1 < 1.f ? 0.5f * d1 * d1 : a1 - 0.5f)
                  + (a2 < 1.f ? 0.5f * d2 * d2 : a2 - 0.5f)
                  + (a3 < 1.f ? 0.5f * d3 * d3 : a3 - 0.5f);
        float2 c = ((const float2*)conf)[gp];
        float mm = fmaxf(c.x, c.y);
        float lse = mm + logf(expf(c.x - mm) + expf(c.y - mm));
        float picked = (cf == 0) ? c.x : c.y;
        float ce = lse - picked;
        if (pos) { s_sl1 += sl1; s_cep += ce; np++; }
        mine[gp] = pos ? 0.f : ce;
    }
#pragma unroll
    for (int m = 32; m; m >>= 1) {
        s_sl1 += __shfl_xor(s_sl1, m, 64);
        s_cep += __shfl_xor(s_cep, m, 64);
        np    += __shfl_xor(np, m, 64);
    }
    int lane = tid & 63, w = tid >> 6;
    if (lane == 0) { rs0[w] = s_sl1; rs1[w] = s_cep; rc[w] = np; }
    __syncthreads();
    if (tid == 0) {
        float t0 = 0.f, t1 = 0.f; int t2 = 0;
        for (int i = 0; i < 4; ++i) { t0 += rs0[i]; t1 += rs1[i]; t2 += rc[i]; }
        atomicAdd(&batch_sl1[b], t0);
        atomicAdd(&batch_cep[b], t1);
        atomicAdd(&batch_npos[b], t2);
    }
}

// ---------------- Kernel C2: register-resident radix-select top-k sum + finalize -------
__launch_bounds__(1024)
__global__ void kernC2(const float* __restrict__ mine,
                       const float* __restrict__ batch_sl1,
                       const float* __restrict__ batch_cep,
                       const int* __restrict__ batch_npos,
                       float* __restrict__ loss_c_total,
                       int* __restrict__ done_cnt,
                       float* __restrict__ out)
{
    const int b = blockIdx.x;
    const int tid = threadIdx.x;
    __shared__ __align__(16) int hist[4][256];
    __shared__ u32 sh_prefix;
    __shared__ int sh_kk;
    __shared__ float rs[16];
    const float* mb = mine + (size_t)b * NP;
    float v[32];
#pragma unroll
    for (int j = 0; j < 8; ++j) {
        float4 t4 = ((const float4*)mb)[j * 1024 + tid];
        v[4 * j] = t4.x; v[4 * j + 1] = t4.y; v[4 * j + 2] = t4.z; v[4 * j + 3] = t4.w;
    }
    const int npos = batch_npos[b];
    const int k = min(7 * npos, NP - 1);
    float topk = 0.f;
    ((int*)hist)[tid] = 0;
    if (tid == 0) { sh_prefix = 0u; sh_kk = k; }
    __syncthreads();
    if (k > 0) {
        for (int pass = 0; pass < 4; ++pass) {
            const int shift = 24 - 8 * pass;
            const u32 prefix = sh_prefix;
#pragma unroll
            for (int j = 0; j < 32; ++j) {
                u32 key = __float_as_uint(v[j]);
                u32 hi = (u32)(((u64)key) >> (shift + 8));  // 64-bit shift: defined at 32
                if (hi == prefix) atomicAdd(&hist[pass][(key >> shift) & 255], 1);
            }
            __syncthreads();
            if (tid < 64) {  // wave 0: parallel suffix-scan bin selection
                int4 h4 = ((const int4*)hist[pass])[tid];
                int s3 = h4.w, s2 = h4.z + s3, s1 = h4.y + s2, s0 = h4.x + s1;
                int acc = s0;
#pragma unroll
                for (int off = 1; off < 64; off <<= 1) {
                    int u = __shfl_down(acc, off, 64);
                    if (tid + off < 64) acc += u;
                }
                int excl = acc - s0;          // count in bins owned by higher lanes
                int kk = sh_kk;
                int cand = -1, nkk = 0;
                if (excl + s3 >= kk)      { cand = 4 * tid + 3; nkk = kk - excl; }
                else if (excl + s2 >= kk) { cand = 4 * tid + 2; nkk = kk - excl - s3; }
                else if (excl + s1 >= kk) { cand = 4 * tid + 1; nkk = kk - excl - s2; }
                else if (excl + s0 >= kk) { cand = 4 * tid + 0; nkk = kk - excl - s1; }
                int cmax = cand;
#pragma unroll
                for (int off = 1; off < 64; off <<= 1) cmax = max(cmax, __shfl_xor(cmax, off, 64));
                if (cand >= 0 && cand == cmax) {   // unique owner lane writes
                    sh_prefix = (prefix << 8) | (u32)(cand & 255);
                    sh_kk = nkk;
                }
            }
            __syncthreads();
        }
        const u32 T = sh_prefix;               // exact k-th largest key
        const float tval = __uint_as_float(T);
        float s = 0.f;
#pragma unroll
        for (int j = 0; j < 32; ++j) {
            if (__float_as_uint(v[j]) > T) s += v[j];
        }
#pragma unroll
        for (int m = 32; m; m >>= 1) s += __shfl_xor(s, m, 64);
        if ((tid & 63) == 0) rs[tid >> 6] = s;
        __syncthreads();
        if (tid == 0) {
            float st = 0.f;
            for (int i = 0; i < 16; ++i) st += rs[i];
            topk = st + (float)sh_kk * tval;   // sh_kk = k - count(>T); ties all equal tval
        }
    }
    if (tid == 0) {
        atomicAdd(loss_c_total, batch_cep[b] + topk);
        __threadfence();
        int done = atomicAdd(done_cnt, 1);
        if (done == NB - 1) {                  // last block finalizes (replaces kernD)
            float lc = atomicAdd(loss_c_total, 0.0f);  // coherent read
            float sl = 0.f; int np = 0;
            for (int i = 0; i < NB; ++i) { sl += batch_sl1[i]; np += batch_npos[i]; }
            float N = fmaxf((float)np, 1.f);
            out[0] = sl / N;
            out[1] = lc / N;
        }
    }
}

extern "C" void kernel_launch(void* const* d_in, const int* in_sizes, int n_in,
                              void* d_out, int out_size, void* d_ws, size_t ws_size,
                              hipStream_t stream) {
    const float* loc     = (const float*)d_in[0];   // (B,P,4)
    const float* conf    = (const float*)d_in[1];   // (B,P,2)
    const float* priors  = (const float*)d_in[2];   // (P,4)
    const float* targets = (const float*)d_in[3];   // (B,O,5)
    float* out = (float*)d_out;

    char* ws = (char*)d_ws;
    u64*   bpk          = (u64*)ws;                          // 0     .. 8192
    float* batch_sl1    = (float*)(ws + 8192);               // 8192  .. 8320
    float* batch_cep    = (float*)(ws + 8320);               // 8320  .. 8448
    int*   batch_npos   = (int*)(ws + 8448);                 // 8448  .. 8576
    float* loss_c_total = (float*)(ws + 8576);               // 8576  .. 8580
    int*   done_cnt     = (int*)(ws + 8580);                 // 8580  .. 8584
    const size_t H = 8704;
    float*         bto  = (float*)(ws + H);                            // 4 MB
    unsigned char* bti  = (unsigned char*)(ws + H + 4ull * NB * NP);   // 1 MB
    float*         mine = (float*)(ws + H + 5ull * NB * NP);           // 4 MB

    hipMemsetAsync(ws, 0, H, stream);

    dim3 gA(NP / 1024, NB);
    kernA<<<gA, 256, 0, stream>>>(priors, targets, bto, bti, bpk);
    kernB<<<1, 1024, 0, stream>>>(bpk, bto, bti);
    dim3 gC(NP / 1024, NB);
    kernC1<<<gC, 256, 0, stream>>>(loc, conf, priors, targets, bto, bti, mine,
                                   batch_sl1, batch_cep, batch_npos);
    kernC2<<<NB, 1024, 0, stream>>>(mine, batch_sl1, batch_cep, batch_npos,
                                    loss_c_total, done_cnt, out);
}

// Round 3
// 158.516 us; speedup vs baseline: 1.6056x; 1.0379x over previous
//
#include <hip/hip_runtime.h>
#include <stdint.h>

#define NB 32
#define NP 32768
#define NO 32
#define THRESH 0.35f

typedef unsigned long long u64;
typedef unsigned int u32;

__device__ __forceinline__ float iou_corners(float px1, float py1, float px2, float py2, float ab,
                                             float tx1, float ty1, float tx2, float ty2, float aa)
{
#pragma clang fp contract(off)
    float iw = fminf(tx2, px2) - fmaxf(tx1, px1);
    float ih = fminf(ty2, py2) - fmaxf(ty1, py1);
    iw = fmaxf(iw, 0.f); ih = fmaxf(ih, 0.f);
    float inter = iw * ih;
    return inter / (aa + ab - inter);
}

// smooth-L1 of (loc - encode(truth, prior)), summed over 4 coords
__device__ __forceinline__ float smooth_l1_sum(float4 ld, float4 pr, float4 tt)
{
#pragma clang fp contract(off)
    float g0 = ((tt.x + tt.z) * 0.5f - pr.x) / (0.1f * pr.z);
    float g1 = ((tt.y + tt.w) * 0.5f - pr.y) / (0.1f * pr.w);
    float g2 = logf((tt.z - tt.x) / pr.z) / 0.2f;
    float g3 = logf((tt.w - tt.y) / pr.w) / 0.2f;
    float d0 = ld.x - g0, d1 = ld.y - g1, d2 = ld.z - g2, d3 = ld.w - g3;
    float a0 = fabsf(d0), a1 = fabsf(d1), a2 = fabsf(d2), a3 = fabsf(d3);
    return (a0 < 1.f ? 0.5f * d0 * d0 : a0 - 0.5f)
         + (a1 < 1.f ? 0.5f * d1 * d1 : a1 - 0.5f)
         + (a2 < 1.f ? 0.5f * d2 * d2 : a2 - 0.5f)
         + (a3 < 1.f ? 0.5f * d3 * d3 : a3 - 0.5f);
}

// ---------------- K1: IoU + per-prior best + PRE-FIX losses + mine, all fused ----------
// grid (32 tiles, 32 batches) x 256 threads; each thread owns 4 CONSECUTIVE priors.
__global__ __launch_bounds__(256) void kern1(
        const float* __restrict__ loc, const float* __restrict__ conf,
        const float* __restrict__ priors, const float* __restrict__ targets,
        float* __restrict__ mine, u64* __restrict__ bpk_part,
        float* __restrict__ part_sl1, float* __restrict__ part_cep, int* __restrict__ part_np)
{
#pragma clang fp contract(off)
    __shared__ __align__(16) float4 tbc[NO];   // truth corners
    __shared__ float ta[NO], tlab[NO];
    __shared__ u64 keys[NO];
    __shared__ float rs0[4], rs1[4];
    __shared__ int rc[4];
    const int b = blockIdx.y, x = blockIdx.x, tid = threadIdx.x;
    if (tid < NO * 5) {
        int o = tid / 5, c = tid % 5;
        float v = targets[b * NO * 5 + tid];
        if (c < 4) ((float*)&tbc[o])[c] = v; else tlab[o] = v;
    }
    __syncthreads();
    if (tid < NO) {
        float4 t = tbc[tid];
        ta[tid] = (t.z - t.x) * (t.w - t.y);
        keys[tid] = 0ull;
    }
    __syncthreads();

    const int p0 = x * 1024 + tid * 4;
    float4 pr[4];
    float px1[4], py1[4], px2[4], py2[4], ab[4];
#pragma unroll
    for (int j = 0; j < 4; ++j) {
        pr[j] = ((const float4*)priors)[p0 + j];
        px1[j] = pr[j].x - pr[j].z * 0.5f;
        py1[j] = pr[j].y - pr[j].w * 0.5f;
        px2[j] = pr[j].x + pr[j].z * 0.5f;
        py2[j] = pr[j].y + pr[j].w * 0.5f;
        ab[j]  = pr[j].z * pr[j].w;
    }
    float bestV[4] = {-1.f, -1.f, -1.f, -1.f};
    int bestO[4] = {0, 0, 0, 0};
    const int lane_o = tid & 31;   // stagger o per lane: spreads keys[] atomics over 32 addrs
    for (int it = 0; it < NO; ++it) {
        const int o = (it + lane_o) & 31;
        float4 tt = tbc[o];
        float aa = ta[o];
        float iou4[4];
#pragma unroll
        for (int j = 0; j < 4; ++j) {
            iou4[j] = iou_corners(px1[j], py1[j], px2[j], py2[j], ab[j],
                                  tt.x, tt.y, tt.z, tt.w, aa);
            // first-max argmax semantics under staggered visit order
            if (iou4[j] > bestV[j] || (iou4[j] == bestV[j] && o < bestO[j])) {
                bestV[j] = iou4[j]; bestO[j] = o;
            }
        }
        // per-truth best prior: local max (smallest p on ties), filtered LDS atomic
        float bi = iou4[3]; int bp = p0 + 3;
#pragma unroll
        for (int j = 2; j >= 0; --j)
            if (iou4[j] >= bi) { bi = iou4[j]; bp = p0 + j; }
        u64 key = ((u64)__float_as_uint(bi) << 32) | (u64)(~(u32)bp);
        if (key > keys[o]) atomicMax(&keys[o], key);
    }

    // ---- pre-fix losses straight from registers ----
    const size_t gbase = (size_t)b * NP + p0;
    float4 cfa = ((const float4*)conf)[gbase / 2];
    float4 cfb = ((const float4*)conf)[gbase / 2 + 1];
    float c0[4] = {cfa.x, cfa.z, cfb.x, cfb.z};
    float c1[4] = {cfa.y, cfa.w, cfb.y, cfb.w};
    float4 mout;
    float s_sl1 = 0.f, s_cep = 0.f;
    int np = 0;
#pragma unroll
    for (int j = 0; j < 4; ++j) {
        float4 ld = ((const float4*)loc)[gbase + j];
        int o = bestO[j];
        int cf = (bestV[j] < THRESH) ? 0 : ((int)tlab[o] + 1);
        bool pos = cf > 0;
        float sl1 = smooth_l1_sum(ld, pr[j], tbc[o]);
        float mm = fmaxf(c0[j], c1[j]);
        float lse = mm + logf(expf(c0[j] - mm) + expf(c1[j] - mm));
        float picked = (cf == 0) ? c0[j] : c1[j];
        float ce = lse - picked;
        if (pos) { s_sl1 += sl1; s_cep += ce; np++; }
        ((float*)&mout)[j] = pos ? 0.f : ce;
    }
    ((float4*)mine)[gbase / 4] = mout;

#pragma unroll
    for (int m = 32; m; m >>= 1) {
        s_sl1 += __shfl_xor(s_sl1, m, 64);
        s_cep += __shfl_xor(s_cep, m, 64);
        np    += __shfl_xor(np, m, 64);
    }
    int lane = tid & 63, w = tid >> 6;
    if (lane == 0) { rs0[w] = s_sl1; rs1[w] = s_cep; rc[w] = np; }
    __syncthreads();
    if (tid == 0) {
        float t0 = 0.f, t1 = 0.f; int t2 = 0;
        for (int i = 0; i < 4; ++i) { t0 += rs0[i]; t1 += rs1[i]; t2 += rc[i]; }
        part_sl1[b * 33 + x] = t0;
        part_cep[b * 33 + x] = t1;
        part_np [b * 33 + x] = t2;
    }
    if (tid < NO) bpk_part[(b * 32 + x) * 32 + tid] = keys[tid];  // after the sync above
}

// ---------------- K2: resolve best-prior-per-truth, apply fix as DELTAS ----------------
// 1 block, 1024 threads = (batch b = tid>>5, truth o = tid&31)
__global__ __launch_bounds__(1024) void kern2(
        const float* __restrict__ loc, const float* __restrict__ conf,
        const float* __restrict__ priors, const float* __restrict__ targets,
        const u64* __restrict__ bpk_part, float* __restrict__ mine,
        float* __restrict__ part_sl1, float* __restrict__ part_cep, int* __restrict__ part_np)
{
#pragma clang fp contract(off)
    __shared__ __align__(16) float4 tbc[NB][NO];
    __shared__ float tlab[NB][NO], tas[NB][NO];
    __shared__ u32 pp[NB][NO];
    const int tid = threadIdx.x;
    for (int i = tid; i < NB * NO * 5; i += 1024) {
        int bo = i / 5, c = i % 5;
        float v = targets[i];
        if (c < 4) ((float*)&tbc[bo >> 5][bo & 31])[c] = v; else tlab[bo >> 5][bo & 31] = v;
    }
    __syncthreads();
    const int b = tid >> 5, o = tid & 31;
    { float4 t = tbc[b][o]; tas[b][o] = (t.z - t.x) * (t.w - t.y); }
    u64 key = 0;
    for (int xx = 0; xx < 32; ++xx) {
        u64 v = bpk_part[(b * 32 + xx) * 32 + o];
        key = v > key ? v : key;
    }
    const u32 p = ~(u32)(key & 0xFFFFFFFFull);
    pp[b][o] = p;
    __syncthreads();
    bool last = true;
    for (int o2 = o + 1; o2 < NO; ++o2)
        if (pp[b][o2] == p) { last = false; break; }   // later o overwrites same prior
    float dsl1 = 0.f, dcep = 0.f; int dnp = 0;
    if (last) {
        float4 prr = ((const float4*)priors)[p];
        float px1 = prr.x - prr.z * 0.5f, py1 = prr.y - prr.w * 0.5f;
        float px2 = prr.x + prr.z * 0.5f, py2 = prr.y + prr.w * 0.5f;
        float ab = prr.z * prr.w;
        // recompute pre-fix best truth for p (natural order, strict > == first-max)
        float bv = -1.f; int bo_ = 0;
        for (int o2 = 0; o2 < NO; ++o2) {
            float4 tt = tbc[b][o2];
            float i2 = iou_corners(px1, py1, px2, py2, ab, tt.x, tt.y, tt.z, tt.w, tas[b][o2]);
            if (i2 > bv) { bv = i2; bo_ = o2; }
        }
        int cf_pre = (bv < THRESH) ? 0 : ((int)tlab[b][bo_] + 1);
        bool pos_pre = cf_pre > 0;
        size_t gp = (size_t)b * NP + p;
        float4 ld = ((const float4*)loc)[gp];
        float2 c = ((const float2*)conf)[gp];
        float mm = fmaxf(c.x, c.y);
        float lse = mm + logf(expf(c.x - mm) + expf(c.y - mm));
        int cf_new = (int)tlab[b][o] + 1;               // forced positive
        dsl1 = smooth_l1_sum(ld, prr, tbc[b][o]);
        dcep = lse - ((cf_new == 0) ? c.x : c.y);
        dnp = 1;
        if (pos_pre) {                                   // remove the pre-fix contribution
            dsl1 -= smooth_l1_sum(ld, prr, tbc[b][bo_]);
            dcep -= lse - ((cf_pre == 0) ? c.x : c.y);
            dnp = 0;
        }
        mine[gp] = 0.f;                                  // fixed prior is pos => mine 0
    }
#pragma unroll
    for (int m = 16; m; m >>= 1) {
        dsl1 += __shfl_xor(dsl1, m, 32);
        dcep += __shfl_xor(dcep, m, 32);
        dnp  += __shfl_xor(dnp, m, 32);
    }
    if (o == 0) {
        part_sl1[b * 33 + 32] = dsl1;
        part_cep[b * 33 + 32] = dcep;
        part_np [b * 33 + 32] = dnp;
    }
}

// ---------------- K3: per-batch register-resident radix-select top-k sum ----------------
__global__ __launch_bounds__(1024) void kern3(
        const float* __restrict__ mine,
        const float* __restrict__ part_sl1, const float* __restrict__ part_cep,
        const int* __restrict__ part_np,
        float* __restrict__ bs, float* __restrict__ bc, int* __restrict__ bn)
{
    const int b = blockIdx.x, tid = threadIdx.x;
    __shared__ __align__(16) int hist[4][256];
    __shared__ u32 sh_prefix;
    __shared__ int sh_kk;
    __shared__ float rs[16];
    __shared__ float sh_sl1, sh_cep;
    __shared__ int sh_np;
    if (tid < 64) {
        float a = (tid < 33) ? part_sl1[b * 33 + tid] : 0.f;
        float d = (tid < 33) ? part_cep[b * 33 + tid] : 0.f;
        int   n = (tid < 33) ? part_np [b * 33 + tid] : 0;
#pragma unroll
        for (int m = 32; m; m >>= 1) {
            a += __shfl_xor(a, m, 64); d += __shfl_xor(d, m, 64); n += __shfl_xor(n, m, 64);
        }
        if (tid == 0) { sh_sl1 = a; sh_cep = d; sh_np = n; sh_prefix = 0u; }
    }
    ((int*)hist)[tid] = 0;
    __syncthreads();
    const int np = sh_np;
    const int k = min(7 * np, NP - 1);
    if (tid == 0) sh_kk = k;
    const float* mb = mine + (size_t)b * NP;
    float v[32];
#pragma unroll
    for (int j = 0; j < 8; ++j) {
        float4 t4 = ((const float4*)mb)[j * 1024 + tid];
        v[4 * j] = t4.x; v[4 * j + 1] = t4.y; v[4 * j + 2] = t4.z; v[4 * j + 3] = t4.w;
    }
    __syncthreads();
    float topk = 0.f;
    if (k > 0) {
        for (int pass = 0; pass < 4; ++pass) {
            const int shift = 24 - 8 * pass;
            const u32 prefix = sh_prefix;
#pragma unroll
            for (int j = 0; j < 32; ++j) {
                u32 keyb = __float_as_uint(v[j]);
                u32 hi = (u32)(((u64)keyb) >> (shift + 8));  // 64-bit shift: defined at 32
                if (hi == prefix) atomicAdd(&hist[pass][(keyb >> shift) & 255], 1);
            }
            __syncthreads();
            if (tid < 64) {  // wave 0: suffix-scan bin selection
                int4 h4 = ((const int4*)hist[pass])[tid];
                int s3 = h4.w, s2 = h4.z + s3, s1 = h4.y + s2, s0 = h4.x + s1;
                int acc = s0;
#pragma unroll
                for (int off = 1; off < 64; off <<= 1) {
                    int u = __shfl_down(acc, off, 64);
                    if (tid + off < 64) acc += u;
                }
                int excl = acc - s0;
                int kk = sh_kk;
                int cand = -1, nkk = 0;
                if (excl + s3 >= kk)      { cand = 4 * tid + 3; nkk = kk - excl; }
                else if (excl + s2 >= kk) { cand = 4 * tid + 2; nkk = kk - excl - s3; }
                else if (excl + s1 >= kk) { cand = 4 * tid + 1; nkk = kk - excl - s2; }
                else if (excl + s0 >= kk) { cand = 4 * tid + 0; nkk = kk - excl - s1; }
                int cmax = cand;
#pragma unroll
                for (int off = 1; off < 64; off <<= 1) cmax = max(cmax, __shfl_xor(cmax, off, 64));
                if (cand >= 0 && cand == cmax) {
                    sh_prefix = (prefix << 8) | (u32)(cand & 255);
                    sh_kk = nkk;
                }
            }
            __syncthreads();
        }
        const u32 T = sh_prefix;
        const float tval = __uint_as_float(T);
        float s = 0.f;
#pragma unroll
        for (int j = 0; j < 32; ++j)
            if (__float_as_uint(v[j]) > T) s += v[j];
#pragma unroll
        for (int m = 32; m; m >>= 1) s += __shfl_xor(s, m, 64);
        if ((tid & 63) == 0) rs[tid >> 6] = s;
        __syncthreads();
        if (tid == 0) {
            float st = 0.f;
            for (int i = 0; i < 16; ++i) st += rs[i];
            topk = st + (float)sh_kk * tval;   // ties at threshold all equal tval
        }
    }
    if (tid == 0) {
        bs[b] = sh_sl1;
        bc[b] = sh_cep + topk;
        bn[b] = sh_np;
    }
}

// ---------------- K4: finalize two scalars ----------------------------------------------
__global__ void kern4(const float* __restrict__ bs, const float* __restrict__ bc,
                      const int* __restrict__ bn, float* __restrict__ out)
{
    int tid = threadIdx.x;
    float s = (tid < NB) ? bs[tid] : 0.f;
    float c = (tid < NB) ? bc[tid] : 0.f;
    int   n = (tid < NB) ? bn[tid] : 0;
#pragma unroll
    for (int m = 32; m; m >>= 1) {
        s += __shfl_xor(s, m, 64);
        c += __shfl_xor(c, m, 64);
        n += __shfl_xor(n, m, 64);
    }
    if (tid == 0) {
        float N = fmaxf((float)n, 1.f);
        out[0] = s / N;
        out[1] = c / N;
    }
}

extern "C" void kernel_launch(void* const* d_in, const int* in_sizes, int n_in,
                              void* d_out, int out_size, void* d_ws, size_t ws_size,
                              hipStream_t stream) {
    const float* loc     = (const float*)d_in[0];   // (B,P,4)
    const float* conf    = (const float*)d_in[1];   // (B,P,2)
    const float* priors  = (const float*)d_in[2];   // (P,4)
    const float* targets = (const float*)d_in[3];   // (B,O,5)
    float* out = (float*)d_out;

    char* ws = (char*)d_ws;
    float* mine     = (float*)ws;                       // 4 MB, written fully by K1
    u64*   bpk_part = (u64*)(ws + 4194304);             // 256 KB [b][x][o], written fully by K1
    float* part_sl1 = (float*)(ws + 4456448);           // [b][33]: x-slots by K1, slot 32 by K2
    float* part_cep = (float*)(ws + 4460672);
    int*   part_np  = (int*)(ws + 4464896);
    float* bs       = (float*)(ws + 4469120);           // per-batch results from K3
    float* bc       = (float*)(ws + 4469248);
    int*   bn       = (int*)(ws + 4469376);

    dim3 g1(32, NB);
    kern1<<<g1, 256, 0, stream>>>(loc, conf, priors, targets, mine, bpk_part,
                                  part_sl1, part_cep, part_np);
    kern2<<<1, 1024, 0, stream>>>(loc, conf, priors, targets, bpk_part, mine,
                                  part_sl1, part_cep, part_np);
    kern3<<<NB, 1024, 0, stream>>>(mine, part_sl1, part_cep, part_np, bs, bc, bn);
    kern4<<<1, 64, 0, stream>>>(bs, bc, bn, out);
}

// Round 4
// 155.746 us; speedup vs baseline: 1.6341x; 1.0178x over previous
//
#include <hip/hip_runtime.h>
#include <stdint.h>

#define NB 32
#define NP 32768
#define NO 32
#define THRESH 0.35f

typedef unsigned long long u64;
typedef unsigned int u32;

// fast IoU from prior corners + truth corners (fast division; identical bits in
// every kernel that calls it — kern1's additions and kern3's delta-subtractions
// must cancel, so both use THIS helper with fp contract off)
__device__ __forceinline__ float iou_corners(float px1, float py1, float px2, float py2, float ab,
                                             float tx1, float ty1, float tx2, float ty2, float aa)
{
#pragma clang fp contract(off)
    float iw = fminf(tx2, px2) - fmaxf(tx1, px1);
    float ih = fminf(ty2, py2) - fmaxf(ty1, py1);
    iw = fmaxf(iw, 0.f); ih = fmaxf(ih, 0.f);
    float inter = iw * ih;
    return __fdividef(inter, aa + ab - inter);
}

// smooth-L1 of (loc - encode(truth, prior)), summed over 4 coords
__device__ __forceinline__ float smooth_l1_sum(float4 ld, float4 pr, float4 tt)
{
#pragma clang fp contract(off)
    float g0 = ((tt.x + tt.z) * 0.5f - pr.x) / (0.1f * pr.z);
    float g1 = ((tt.y + tt.w) * 0.5f - pr.y) / (0.1f * pr.w);
    float g2 = __logf((tt.z - tt.x) / pr.z) / 0.2f;
    float g3 = __logf((tt.w - tt.y) / pr.w) / 0.2f;
    float d0 = ld.x - g0, d1 = ld.y - g1, d2 = ld.z - g2, d3 = ld.w - g3;
    float a0 = fabsf(d0), a1 = fabsf(d1), a2 = fabsf(d2), a3 = fabsf(d3);
    return (a0 < 1.f ? 0.5f * d0 * d0 : a0 - 0.5f)
         + (a1 < 1.f ? 0.5f * d1 * d1 : a1 - 0.5f)
         + (a2 < 1.f ? 0.5f * d2 * d2 : a2 - 0.5f)
         + (a3 < 1.f ? 0.5f * d3 * d3 : a3 - 0.5f);
}

__device__ __forceinline__ float lse2(float c0, float c1)
{
#pragma clang fp contract(off)
    float mm = fmaxf(c0, c1), mn = fminf(c0, c1);
    return mm + __logf(1.f + __expf(mn - mm));
}

// ---------------- K1: IoU + per-prior best + PRE-FIX losses + mine, all fused ----------
// grid (32 tiles, 32 batches) x 256 threads; each thread owns 4 CONSECUTIVE priors.
__global__ __launch_bounds__(256) void kern1(
        const float* __restrict__ loc, const float* __restrict__ conf,
        const float* __restrict__ priors, const float* __restrict__ targets,
        float* __restrict__ mine, u64* __restrict__ bpk_part,
        float* __restrict__ part_sl1, float* __restrict__ part_cep, int* __restrict__ part_np)
{
#pragma clang fp contract(off)
    __shared__ __align__(16) float4 tbc[NO];   // truth corners
    __shared__ float ta[NO], tlab[NO];
    __shared__ u64 keys[NO];
    __shared__ float rs0[4], rs1[4];
    __shared__ int rc[4];
    const int b = blockIdx.y, x = blockIdx.x, tid = threadIdx.x;
    if (tid < NO * 5) {
        int o = tid / 5, c = tid % 5;
        float v = targets[b * NO * 5 + tid];
        if (c < 4) ((float*)&tbc[o])[c] = v; else tlab[o] = v;
    }
    if (tid < NO) keys[tid] = 0ull;
    __syncthreads();
    if (tid < NO) {
        float4 t = tbc[tid];
        ta[tid] = (t.z - t.x) * (t.w - t.y);
    }
    __syncthreads();

    const int p0 = x * 1024 + tid * 4;
    float4 pr[4];
    float px1[4], py1[4], px2[4], py2[4], ab[4];
#pragma unroll
    for (int j = 0; j < 4; ++j) {
        pr[j] = ((const float4*)priors)[p0 + j];
        px1[j] = pr[j].x - pr[j].z * 0.5f;
        py1[j] = pr[j].y - pr[j].w * 0.5f;
        px2[j] = pr[j].x + pr[j].z * 0.5f;
        py2[j] = pr[j].y + pr[j].w * 0.5f;
        ab[j]  = pr[j].z * pr[j].w;
    }
    // per-prior best truth as packed u64: (iou_bits << 6) | (63 - o)
    // max => largest iou, tie => smallest o (reference first-max argmax)
    u64 bk[4] = {0ull, 0ull, 0ull, 0ull};
    const int lane_o = tid & 31;   // stagger o per lane: spreads keys[] traffic over 32 addrs
    for (int it = 0; it < NO; ++it) {
        const int o = (it + lane_o) & 31;
        float4 tt = tbc[o];
        float aa = ta[o];
        float iou4[4];
#pragma unroll
        for (int j = 0; j < 4; ++j) {
            float iou = iou_corners(px1[j], py1[j], px2[j], py2[j], ab[j],
                                    tt.x, tt.y, tt.z, tt.w, aa);
            iou4[j] = iou;
            u64 ko = ((u64)__float_as_uint(iou) << 6) | (u64)(63 - o);
            bk[j] = bk[j] > ko ? bk[j] : ko;
        }
        // per-truth best prior: cheap value-only filter, rare full path
        float vm = fmaxf(fmaxf(iou4[0], iou4[1]), fmaxf(iou4[2], iou4[3]));
        u32 vb = __float_as_uint(vm);
        u64 cur = keys[o];
        if (vb > (u32)(cur >> 32)) {
            float bi = iou4[3]; int bp = p0 + 3;
            if (iou4[2] >= bi) { bi = iou4[2]; bp = p0 + 2; }
            if (iou4[1] >= bi) { bi = iou4[1]; bp = p0 + 1; }
            if (iou4[0] >= bi) { bi = iou4[0]; bp = p0 + 0; }
            atomicMax(&keys[o], ((u64)__float_as_uint(bi) << 32) | (u64)(~(u32)bp));
        }
    }

    // ---- pre-fix losses straight from registers ----
    const size_t gbase = (size_t)b * NP + p0;
    float4 cfa = ((const float4*)conf)[gbase / 2];
    float4 cfb = ((const float4*)conf)[gbase / 2 + 1];
    float c0[4] = {cfa.x, cfa.z, cfb.x, cfb.z};
    float c1[4] = {cfa.y, cfa.w, cfb.y, cfb.w};
    float4 mout;
    float s_sl1 = 0.f, s_cep = 0.f;
    int np = 0;
#pragma unroll
    for (int j = 0; j < 4; ++j) {
        u32 vb = (u32)(bk[j] >> 6);
        float bv = __uint_as_float(vb);
        int o = 63 - (int)(bk[j] & 63);
        int cf = (bv < THRESH) ? 0 : ((int)tlab[o] + 1);
        bool pos = cf > 0;
        float4 ld = ((const float4*)loc)[gbase + j];
        float sl1 = smooth_l1_sum(ld, pr[j], tbc[o]);
        float ce = lse2(c0[j], c1[j]) - ((cf == 0) ? c0[j] : c1[j]);
        if (pos) { s_sl1 += sl1; s_cep += ce; np++; }
        ((float*)&mout)[j] = pos ? 0.f : ce;
    }
    ((float4*)mine)[gbase / 4] = mout;

#pragma unroll
    for (int m = 32; m; m >>= 1) {
        s_sl1 += __shfl_xor(s_sl1, m, 64);
        s_cep += __shfl_xor(s_cep, m, 64);
        np    += __shfl_xor(np, m, 64);
    }
    int lane = tid & 63, w = tid >> 6;
    if (lane == 0) { rs0[w] = s_sl1; rs1[w] = s_cep; rc[w] = np; }
    __syncthreads();
    if (tid == 0) {
        float t0 = 0.f, t1 = 0.f; int t2 = 0;
        for (int i = 0; i < 4; ++i) { t0 += rs0[i]; t1 += rs1[i]; t2 += rc[i]; }
        part_sl1[b * 32 + x] = t0;
        part_cep[b * 32 + x] = t1;
        part_np [b * 32 + x] = t2;
    }
    if (tid < NO) bpk_part[(b * 32 + x) * 32 + tid] = keys[tid];  // after the sync above
}

// ---------------- K3: fix-resolution + deltas + register radix-select top-k -------------
// one block per batch, 1024 threads
__global__ __launch_bounds__(1024) void kern3(
        const float* __restrict__ loc, const float* __restrict__ conf,
        const float* __restrict__ priors, const float* __restrict__ targets,
        const u64* __restrict__ bpk_part, const float* __restrict__ mine,
        const float* __restrict__ part_sl1, const float* __restrict__ part_cep,
        const int* __restrict__ part_np,
        float* __restrict__ bs, float* __restrict__ bc, int* __restrict__ bn)
{
#pragma clang fp contract(off)
    const int b = blockIdx.x, tid = threadIdx.x;
    __shared__ __align__(16) float4 tbc[NO];
    __shared__ float tlab[NO], tas[NO];
    __shared__ u32 pp[NO];
    __shared__ u32 flags[1024];                 // 32768-bit mask of forced priors
    __shared__ __align__(16) int h0[256];
    __shared__ __align__(16) int h1[4096];
    __shared__ __align__(16) int h2[4096];
    __shared__ u32 sh_prefix;
    __shared__ int sh_kk;
    __shared__ float sh_sl1, sh_cep;
    __shared__ int sh_np;
    __shared__ float rs[16];

    if (tid < NO * 5) {
        int o = tid / 5, c = tid % 5;
        float v = targets[b * NO * 5 + tid];
        if (c < 4) ((float*)&tbc[o])[c] = v; else tlab[o] = v;
    }
    flags[tid] = 0u;
    if (tid < 256) h0[tid] = 0;
    for (int i = tid; i < 4096; i += 1024) { h1[i] = 0; h2[i] = 0; }

    const float* mb = mine + (size_t)b * NP;
    float v[32];
#pragma unroll
    for (int q = 0; q < 8; ++q) {
        float4 t4 = ((const float4*)mb)[q * 1024 + tid];
        v[4 * q] = t4.x; v[4 * q + 1] = t4.y; v[4 * q + 2] = t4.z; v[4 * q + 3] = t4.w;
    }
    __syncthreads();
    if (tid < NO) {
        float4 t = tbc[tid];
        tas[tid] = (t.z - t.x) * (t.w - t.y);
        // resolve per-truth best prior across the 32 x-tiles (strict > keeps u64-max;
        // value ties resolved by ~p inside the key => smallest p, matches reference)
        u64 key = 0ull;
        for (int xx = 0; xx < 32; ++xx) {
            u64 t2 = bpk_part[(b * 32 + xx) * 32 + tid];
            key = t2 > key ? t2 : key;
        }
        pp[tid] = (key >> 32) ? ~(u32)key : 0u;   // all-zero row => argmax = 0 (safety)
    }
    __syncthreads();
    float dsl1 = 0.f, dcep = 0.f; int dnp = 0;
    if (tid < NO) {
        const int o = tid;
        const u32 p = pp[o];
        bool last = true;
        for (int o2 = o + 1; o2 < NO; ++o2)
            if (pp[o2] == p) { last = false; break; }   // later o overwrites same prior
        if (last) {
            float4 prr = ((const float4*)priors)[p];
            float px1 = prr.x - prr.z * 0.5f, py1 = prr.y - prr.w * 0.5f;
            float px2 = prr.x + prr.z * 0.5f, py2 = prr.y + prr.w * 0.5f;
            float ab = prr.z * prr.w;
            // pre-fix best truth for p (natural order, strict > == first-max; same
            // winner as kern1's staggered u64-key argmax for identical bits)
            float bv = -1.f; int bo_ = 0;
            for (int o2 = 0; o2 < NO; ++o2) {
                float4 t2 = tbc[o2];
                float i2 = iou_corners(px1, py1, px2, py2, ab, t2.x, t2.y, t2.z, t2.w, tas[o2]);
                if (i2 > bv) { bv = i2; bo_ = o2; }
            }
            int cf_pre = (bv < THRESH) ? 0 : ((int)tlab[bo_] + 1);
            size_t gp = (size_t)b * NP + p;
            float4 ld = ((const float4*)loc)[gp];
            float2 c = ((const float2*)conf)[gp];
            float lse = lse2(c.x, c.y);
            int cf_new = (int)tlab[o] + 1;               // forced positive
            dsl1 = smooth_l1_sum(ld, prr, tbc[o]);
            dcep = lse - ((cf_new == 0) ? c.x : c.y);
            dnp = 1;
            if (cf_pre > 0) {                            // remove pre-fix contribution
                dsl1 -= smooth_l1_sum(ld, prr, tbc[bo_]);
                dcep -= lse - ((cf_pre == 0) ? c.x : c.y);
                dnp = 0;
            }
            atomicOr(&flags[p >> 5], 1u << (p & 31));
        }
        // batch stats: 32 kern1 partials + this lane's delta, wave-0 reduce
        float a = part_sl1[b * 32 + o] + dsl1;
        float d = part_cep[b * 32 + o] + dcep;
        int   n = part_np [b * 32 + o] + dnp;
#pragma unroll
        for (int m = 16; m; m >>= 1) {
            a += __shfl_xor(a, m, 32);
            d += __shfl_xor(d, m, 32);
            n += __shfl_xor(n, m, 32);
        }
        if (o == 0) {
            sh_sl1 = a; sh_cep = d; sh_np = n;
            sh_prefix = 0u; sh_kk = min(7 * n, NP - 1);
        }
    }
    __syncthreads();
    // zero forced priors in-register (they become pos => mine 0)
#pragma unroll
    for (int q = 0; q < 8; ++q) {
        u32 word = flags[q * 128 + (tid >> 3)];
#pragma unroll
        for (int c = 0; c < 4; ++c)
            if ((word >> (((tid & 7) << 2) + c)) & 1u) v[4 * q + c] = 0.f;
    }
    const int k = sh_kk;
    const int lane = tid & 63;
    float topk = 0.f;
    if (k > 0) {
        // ---- pass 0: bits[31:24], ballot-aggregated (bins concentrate in ~5 exponents) ----
#pragma unroll 4
        for (int j = 0; j < 32; ++j) {
            u32 bin = __float_as_uint(v[j]) >> 24;
            u64 todo = ~0ull;
            while (todo) {
                int leader = __ffsll((unsigned long long)todo) - 1;
                u32 lb = (u32)__shfl((int)bin, leader, 64);
                u64 mt = __ballot(bin == lb);
                if (lane == leader) atomicAdd(&h0[lb], (int)__popcll(mt));
                todo &= ~mt;
            }
        }
        __syncthreads();
        if (tid < 64) {   // suffix-scan select over 256 bins
            int4 h4 = ((const int4*)h0)[tid];
            int s3 = h4.w, s2 = h4.z + s3, s1 = h4.y + s2, s0 = h4.x + s1;
            int acc = s0;
#pragma unroll
            for (int off = 1; off < 64; off <<= 1) {
                int u = __shfl_down(acc, off, 64);
                if (tid + off < 64) acc += u;
            }
            int excl = acc - s0;
            int kk = sh_kk;
            int cand = -1, nkk = 0;
            if (excl + s3 >= kk)      { cand = 4 * tid + 3; nkk = kk - excl; }
            else if (excl + s2 >= kk) { cand = 4 * tid + 2; nkk = kk - excl - s3; }
            else if (excl + s1 >= kk) { cand = 4 * tid + 1; nkk = kk - excl - s2; }
            else if (excl + s0 >= kk) { cand = 4 * tid + 0; nkk = kk - excl - s1; }
            int cmax = cand;
#pragma unroll
            for (int off = 1; off < 64; off <<= 1) cmax = max(cmax, __shfl_xor(cmax, off, 64));
            if (cand >= 0 && cand == cmax) { sh_prefix = (u32)cand; sh_kk = nkk; }
        }
        __syncthreads();
        // ---- pass 1: bits[23:12], 4096 bins, direct atomics (values now spread) ----
        {
            const u32 pfx = sh_prefix;
#pragma unroll 4
            for (int j = 0; j < 32; ++j) {
                u32 kb = __float_as_uint(v[j]);
                if ((kb >> 24) == pfx) atomicAdd(&h1[(kb >> 12) & 0xFFF], 1);
            }
            __syncthreads();
            if (tid < 64) {   // lane owns 64 bins
                int tot = 0;
#pragma unroll
                for (int q = 0; q < 16; ++q) {
                    int4 xq = ((const int4*)h1)[tid * 16 + q];
                    tot += xq.x + xq.y + xq.z + xq.w;
                }
                int acc = tot;
#pragma unroll
                for (int off = 1; off < 64; off <<= 1) {
                    int u = __shfl_down(acc, off, 64);
                    if (tid + off < 64) acc += u;
                }
                int excl = acc - tot;
                int kk = sh_kk;
                if (excl < kk && excl + tot >= kk) {     // exactly one crossing lane
                    int a2 = excl, sel = 0, nkk = 0; bool fnd = false;
                    for (int i = 63; i >= 0; --i) {
                        int cbin = h1[tid * 64 + i];
                        if (!fnd && a2 + cbin >= kk) { sel = i; nkk = kk - a2; fnd = true; }
                        a2 += cbin;
                    }
                    sh_prefix = (pfx << 12) | (u32)(tid * 64 + sel);
                    sh_kk = nkk;
                }
            }
            __syncthreads();
        }
        // ---- pass 2: bits[11:0], 4096 bins ----
        {
            const u32 pfx = sh_prefix;   // 20 bits
#pragma unroll 4
            for (int j = 0; j < 32; ++j) {
                u32 kb = __float_as_uint(v[j]);
                if ((kb >> 12) == pfx) atomicAdd(&h2[kb & 0xFFF], 1);
            }
            __syncthreads();
            if (tid < 64) {
                int tot = 0;
#pragma unroll
                for (int q = 0; q < 16; ++q) {
                    int4 xq = ((const int4*)h2)[tid * 16 + q];
                    tot += xq.x + xq.y + xq.z + xq.w;
                }
                int acc = tot;
#pragma unroll
                for (int off = 1; off < 64; off <<= 1) {
                    int u = __shfl_down(acc, off, 64);
                    if (tid + off < 64) acc += u;
                }
                int excl = acc - tot;
                int kk = sh_kk;
                if (excl < kk && excl + tot >= kk) {
                    int a2 = excl, sel = 0, nkk = 0; bool fnd = false;
                    for (int i = 63; i >= 0; --i) {
                        int cbin = h2[tid * 64 + i];
                        if (!fnd && a2 + cbin >= kk) { sel = i; nkk = kk - a2; fnd = true; }
                        a2 += cbin;
                    }
                    sh_prefix = (pfx << 12) | (u32)(tid * 64 + sel);
                    sh_kk = nkk;
                }
            }
            __syncthreads();
        }
        const u32 T = sh_prefix;               // exact k-th largest key
        const float tval = __uint_as_float(T);
        float s = 0.f;
#pragma unroll
        for (int j = 0; j < 32; ++j)
            if (__float_as_uint(v[j]) > T) s += v[j];
#pragma unroll
        for (int m = 32; m; m >>= 1) s += __shfl_xor(s, m, 64);
        if (lane == 0) rs[tid >> 6] = s;
        __syncthreads();
        if (tid == 0) {
            float st = 0.f;
            for (int i = 0; i < 16; ++i) st += rs[i];
            topk = st + (float)sh_kk * tval;   // sh_kk = #ties at T still selected
        }
    }
    if (tid == 0) {
        bs[b] = sh_sl1;
        bc[b] = sh_cep + topk;
        bn[b] = sh_np;
    }
}

// ---------------- K4: finalize two scalars ----------------------------------------------
__global__ void kern4(const float* __restrict__ bs, const float* __restrict__ bc,
                      const int* __restrict__ bn, float* __restrict__ out)
{
    int tid = threadIdx.x;
    float s = (tid < NB) ? bs[tid] : 0.f;
    float c = (tid < NB) ? bc[tid] : 0.f;
    int   n = (tid < NB) ? bn[tid] : 0;
#pragma unroll
    for (int m = 32; m; m >>= 1) {
        s += __shfl_xor(s, m, 64);
        c += __shfl_xor(c, m, 64);
        n += __shfl_xor(n, m, 64);
    }
    if (tid == 0) {
        float N = fmaxf((float)n, 1.f);
        out[0] = s / N;
        out[1] = c / N;
    }
}

extern "C" void kernel_launch(void* const* d_in, const int* in_sizes, int n_in,
                              void* d_out, int out_size, void* d_ws, size_t ws_size,
                              hipStream_t stream) {
    const float* loc     = (const float*)d_in[0];   // (B,P,4)
    const float* conf    = (const float*)d_in[1];   // (B,P,2)
    const float* priors  = (const float*)d_in[2];   // (P,4)
    const float* targets = (const float*)d_in[3];   // (B,O,5)
    float* out = (float*)d_out;

    char* ws = (char*)d_ws;
    float* mine     = (float*)ws;                       // 4 MB, fully written by K1
    u64*   bpk_part = (u64*)(ws + 4194304);             // 256 KB [b][x][o], fully written by K1
    float* part_sl1 = (float*)(ws + 4456448);           // [b][32] kern1 partials
    float* part_cep = (float*)(ws + 4460544);
    int*   part_np  = (int*)(ws + 4464640);
    float* bs       = (float*)(ws + 4468736);           // per-batch results from K3
    float* bc       = (float*)(ws + 4468864);
    int*   bn       = (int*)(ws + 4468992);

    dim3 g1(32, NB);
    kern1<<<g1, 256, 0, stream>>>(loc, conf, priors, targets, mine, bpk_part,
                                  part_sl1, part_cep, part_np);
    kern3<<<NB, 1024, 0, stream>>>(loc, conf, priors, targets, bpk_part, mine,
                                   part_sl1, part_cep, part_np, bs, bc, bn);
    kern4<<<1, 64, 0, stream>>>(bs, bc, bn, out);
}